// Round 21
// baseline (71.735 us; speedup 1.0000x reference)
//
#include <hip/hip_runtime.h>
#include <cstddef>

typedef __attribute__((ext_vector_type(8))) __bf16 bf16x8;
typedef __attribute__((ext_vector_type(4))) float f32x4;
typedef unsigned short u16;
typedef unsigned int   u32;

#define SCLF (0.125f * 1.44269504f)   // softmax scale * log2(e), baked into q' master weights

// ---------- helpers ----------
__device__ __forceinline__ u16 f2bf(float f){
  union { float f; u32 u; } v; v.f = f;
  u32 r = v.u + 0x7FFFu + ((v.u >> 16) & 1u);   // RNE
  return (u16)(r >> 16);
}
__device__ __forceinline__ u32 cvtpk(float lo, float hi){
  u32 r; asm("v_cvt_pk_bf16_f32 %0, %1, %2" : "=v"(r) : "v"(lo), "v"(hi)); return r;
}
__device__ __forceinline__ void gll16(const void* g, void* l){
  __builtin_amdgcn_global_load_lds((__attribute__((address_space(1))) void*)g,
                                   (__attribute__((address_space(3))) void*)l, 16, 0, 0);
}
#define BARRIER() asm volatile("s_barrier" ::: "memory")
#define WAITV4()  asm volatile("s_waitcnt vmcnt(4)" ::: "memory")
#define WAITV0()  asm volatile("s_waitcnt vmcnt(0)" ::: "memory")

// ---------- prep_x: x fp32->bf16 (1024 blocks, 4 float4/thread) + bias fold (3 blocks) ----------
__global__ __launch_bounds__(256) void prep_x(const float* __restrict__ x,
      const float* __restrict__ ba, const float* __restrict__ kc,
      const float* __restrict__ ke, const float* __restrict__ vc,
      u16* __restrict__ Xb, float* __restrict__ b2){
  __shared__ float SH[3104];           // BaL[1024] + W65[32*65] = 12416 B
  const int bid = blockIdx.x, tid = threadIdx.x;
  if (bid < 1024){
    int i0 = bid*1024 + tid;
    #pragma unroll
    for (int t=0;t<4;++t){
      int i = i0 + t*256;
      float4 v = ((const float4*)x)[i];
      uint2 r; r.x = cvtpk(v.x, v.y); r.y = cvtpk(v.z, v.w);
      ((uint2*)Xb)[i] = r;
    }
  } else {
    const int part = bid - 1024;
    float* BaL = SH;                   // [1024]
    float* W65 = SH + 1024;            // [32][65]
    *(float4*)&BaL[tid*4] = *(const float4*)&ba[part*1024 + tid*4];
    {
      const float* msrc = (part==0) ? ke : (part==1) ? kc : vc;
      #pragma unroll
      for (int i=0;i<8;++i){
        int idx = tid + i*256;
        float v = msrc[idx];
        int r, d;
        if (part == 0){ r = idx >> 6; d = idx & 63; }
        else          { d = idx >> 5; r = idx & 31; }
        W65[r*65 + d] = v;
      }
    }
    __syncthreads();
    const float scl = (part==0) ? SCLF : 1.f;
    #pragma unroll
    for (int t=0;t<2;++t){
      int l = tid + t*256;
      int hh = l >> 5, r = l & 31;
      float acc = 0.f;
      for (int d=0;d<64;++d) acc += BaL[hh*64 + d] * W65[r*65 + d];
      b2[part*512 + l] = acc * scl;
    }
  }
}

// ---------- fold_f32: weight folds reading f32 inputs directly ----------
// grid (16 cc, 64 y): y<48 qkv fold (ph=y), y>=48 proj fold (ph=y-48).
__global__ __launch_bounds__(256) void fold_f32(const float* __restrict__ Wa,
      const float* __restrict__ Wp, const float* __restrict__ kc,
      const float* __restrict__ ke, const float* __restrict__ vc,
      const float* __restrict__ ve, u16* __restrict__ Wt, u16* __restrict__ W2t){
  __shared__ __align__(16) char PS[28928];   // SH f32 [64][65] | As [64][64] u16 | Bs [32][64] u16
  float* SH = (float*)PS;
  u16* As = (u16*)(PS + 16640);
  u16* Bs = (u16*)(PS + 16640 + 8192);
  const int cc = blockIdx.x, y = blockIdx.y;
  const int tid = threadIdx.x;
  const int wv = tid>>6, ln = tid&63;
  const int lr = ln&15, g8 = (ln>>4)*8, gq = ln>>4;
  const int swz = (lr&7)*8;
  const int c0 = cc*64;

  if (y < 48){                         // ---- qkv fold ----
    const int ph = y;
    const int part = ph >> 4;
    {
      int r = tid>>3, d8 = tid&7;
      float v[8];
      if (part == 0){
        #pragma unroll
        for (int j=0;j<8;++j) v[j] = ke[r*64 + d8*8 + j]*SCLF;
      } else {
        const float* m = (part==1) ? kc : vc;
        #pragma unroll
        for (int j=0;j<8;++j) v[j] = m[(d8*8+j)*32 + r];
      }
      uint4 w; w.x=cvtpk(v[0],v[1]); w.y=cvtpk(v[2],v[3]); w.z=cvtpk(v[4],v[5]); w.w=cvtpk(v[6],v[7]);
      *(uint4*)&Bs[r*64 + ((d8 ^ (r&7))*8)] = w;
    }
    #pragma unroll
    for (int p=0;p<2;++p){
      int g2 = p*256 + tid;
      int row = g2>>3, gcol = g2&7;
      const float* src = Wa + (size_t)(c0+row)*3072 + ph*64 + gcol*8;
      float4 a = ((const float4*)src)[0], b = ((const float4*)src)[1];
      uint4 w; w.x=cvtpk(a.x,a.y); w.y=cvtpk(a.z,a.w); w.z=cvtpk(b.x,b.y); w.w=cvtpk(b.z,b.w);
      *(uint4*)&As[row*64 + ((gcol ^ (row&7))*8)] = w;
    }
    __syncthreads();
    f32x4 acc[2] = {};
    const int wr = (wv>>1)*32, wn = wv&1;
    #pragma unroll
    for (int ks=0;ks<2;++ks){
      int off = (ks*32 + g8) ^ swz;
      bf16x8 bf = *(const bf16x8*)&Bs[(wn*16+lr)*64 + off];
      #pragma unroll
      for (int mt=0;mt<2;++mt){
        bf16x8 af = *(const bf16x8*)&As[(wr+mt*16+lr)*64 + off];
        acc[mt] = __builtin_amdgcn_mfma_f32_16x16x32_bf16(af, bf, acc[mt], 0,0,0);
      }
    }
    const int n = part*512 + (ph&15)*32 + wn*16 + lr;
    #pragma unroll
    for (int mt=0;mt<2;++mt){
      union { u16 s[4]; uint2 v; } pk;
      #pragma unroll
      for (int r=0;r<4;++r) pk.s[r] = f2bf(acc[mt][r]);
      *(uint2*)&Wt[(size_t)n*1024 + c0 + wr + mt*16 + 4*gq] = pk.v;
    }
  } else {                             // ---- proj fold ----
    const int ph = y - 48;                       // 0..15
    {
      int r = tid>>2, c4 = (tid&3)*16;
      const float* src = Wp + (size_t)(ph*64 + r)*1024 + c0 + c4;
      float4 v0 = ((const float4*)src)[0], v1 = ((const float4*)src)[1],
             v2 = ((const float4*)src)[2], v3 = ((const float4*)src)[3];
      float* dst = &SH[r*65 + c4];
      dst[0]=v0.x; dst[1]=v0.y; dst[2]=v0.z; dst[3]=v0.w;
      dst[4]=v1.x; dst[5]=v1.y; dst[6]=v1.z; dst[7]=v1.w;
      dst[8]=v2.x; dst[9]=v2.y; dst[10]=v2.z; dst[11]=v2.w;
      dst[12]=v3.x; dst[13]=v3.y; dst[14]=v3.z; dst[15]=v3.w;
    }
    {
      int r = tid>>3, d8 = tid&7;
      float v[8];
      #pragma unroll
      for (int j=0;j<8;++j) v[j] = ve[r*64 + d8*8 + j];
      uint4 w; w.x=cvtpk(v[0],v[1]); w.y=cvtpk(v[2],v[3]); w.z=cvtpk(v[4],v[5]); w.w=cvtpk(v[6],v[7]);
      *(uint4*)&Bs[r*64 + ((d8 ^ (r&7))*8)] = w;
    }
    __syncthreads();
    #pragma unroll
    for (int p=0;p<2;++p){
      int g2 = p*256 + tid;
      int j = g2>>3, d8 = g2&7;
      float v[8];
      #pragma unroll
      for (int jj=0;jj<8;++jj) v[jj] = SH[(d8*8+jj)*65 + j];
      uint4 w; w.x=cvtpk(v[0],v[1]); w.y=cvtpk(v[2],v[3]); w.z=cvtpk(v[4],v[5]); w.w=cvtpk(v[6],v[7]);
      *(uint4*)&As[j*64 + ((d8 ^ (j&7))*8)] = w;
    }
    __syncthreads();
    f32x4 acc[2] = {};
    const int wr = (wv>>1)*32, wn = wv&1;
    #pragma unroll
    for (int ks=0;ks<2;++ks){
      int off = (ks*32 + g8) ^ swz;
      bf16x8 bf = *(const bf16x8*)&Bs[(wn*16+lr)*64 + off];
      #pragma unroll
      for (int mt=0;mt<2;++mt){
        bf16x8 af = *(const bf16x8*)&As[(wr+mt*16+lr)*64 + off];
        acc[mt] = __builtin_amdgcn_mfma_f32_16x16x32_bf16(af, bf, acc[mt], 0,0,0);
      }
    }
    const int col = ph*32 + wn*16 + lr;
    #pragma unroll
    for (int mt=0;mt<2;++mt)
      #pragma unroll
      for (int r=0;r<4;++r)
        W2t[(size_t)(c0 + wr + mt*16 + 4*gq + r)*512 + col] = f2bf(acc[mt][r]);
  }
}

// ---------- 128x128 bf16 GEMM (4 waves of 64x64, gll16, T2 swizzle): gemm1 ----------
// Better MFMA:ds_read ratio (0.5 vs 0.75 for 64x128). Fused Vt epilogue for n0>=1024.
template<typename OT>
__global__ __launch_bounds__(256) void gemm128(const u16* __restrict__ A, const u16* __restrict__ Bt,
        const float* __restrict__ bias, OT* __restrict__ C, u16* __restrict__ Vt,
        int M, int N, int K, int ldc){
  __shared__ u16 As[128*64];
  __shared__ u16 Bs[128*64];
  const int nwg = gridDim.x * gridDim.y;
  const int id  = blockIdx.x + gridDim.x * blockIdx.y;
  const int nid = (id & 7) * (nwg >> 3) + (id >> 3);   // nwg % 8 == 0
  const int bx = nid % gridDim.x, by = nid / gridDim.x;
  const int tid = threadIdx.x, wv = tid>>6, ln = tid&63;
  const int lr = ln&15, g8 = (ln>>4)*8;
  const int m0 = bx*128, n0 = by*128;
  const int wr = (wv>>1)*64, wc = (wv&1)*64;
  const int lrow = ln>>3, lcol = ((ln&7) ^ lrow)*8;   // pre-swizzled source col
  const int swz = (lr&7)*8;
  f32x4 acc[4][4] = {};
  const int nk = K >> 6;
  for (int kt=0; kt<nk; ++kt){
    #pragma unroll
    for (int it=0; it<8; ++it){
      int chunk = wv*8 + it;                // 0..31: first 16 A, rest B
      if (chunk < 16){
        int row = chunk*8 + lrow;
        gll16(A + (size_t)(m0+row)*K + kt*64 + lcol, &As[chunk*512]);
      } else {
        int bc = chunk - 16;
        int row = bc*8 + lrow;
        gll16(Bt + (size_t)(n0+row)*K + kt*64 + lcol, &Bs[bc*512]);
      }
    }
    __syncthreads();
    #pragma unroll
    for (int ks=0; ks<2; ++ks){
      int off = (ks*32 + g8) ^ swz;
      bf16x8 af[4], bfr[4];
      #pragma unroll
      for (int mt=0;mt<4;++mt) af[mt]  = *(const bf16x8*)&As[(wr+mt*16+lr)*64 + off];
      #pragma unroll
      for (int nt=0;nt<4;++nt) bfr[nt] = *(const bf16x8*)&Bs[(wc+nt*16+lr)*64 + off];
      #pragma unroll
      for (int mt=0;mt<4;++mt)
        #pragma unroll
        for (int nt=0;nt<4;++nt)
          acc[mt][nt] = __builtin_amdgcn_mfma_f32_16x16x32_bf16(af[mt], bfr[nt], acc[mt][nt], 0,0,0);
    }
    __syncthreads();
  }
  if (Vt && n0 >= 1024){
    #pragma unroll
    for (int mt=0;mt<4;++mt){
      int row0 = m0 + wr + mt*16 + 4*(ln>>4);
      int tin  = row0 & 2047;
      int p0 = 4*((tin>>4)&1) + 8*((tin>>2)&3) + 32*(tin>>5);
      size_t vbase = (size_t)(row0 >> 11) * 512;
      #pragma unroll
      for (int nt=0;nt<4;++nt){
        int col = n0 + wc + nt*16 + lr;
        float bv = bias[col];
        int nlat = col - 1024;
        union { u16 s[4]; uint2 v; } pk;
        #pragma unroll
        for (int r=0;r<4;++r) pk.s[r] = f2bf(acc[mt][nt][r] + bv);
        *(uint2*)&Vt[(vbase + nlat)*2048 + p0] = pk.v;
      }
    }
  } else {
    #pragma unroll
    for (int mt=0;mt<4;++mt){
      int row = m0 + wr + mt*16 + 4*(ln>>4);
      #pragma unroll
      for (int nt=0;nt<4;++nt){
        int col = n0 + wc + nt*16 + lr;
        float bv = bias[col];
        #pragma unroll
        for (int r=0;r<4;++r){
          float v = acc[mt][nt][r] + bv;
          if constexpr (sizeof(OT) == 2) C[(size_t)(row+r)*ldc + col] = f2bf(v);
          else                           C[(size_t)(row+r)*ldc + col] = v;
        }
      }
    }
  }
}

// ---------- 64x128 bf16 GEMM (2-phase, gll16, T2-swizzled LDS): gemm2 ----------
template<typename OT>
__global__ __launch_bounds__(256) void gemm64(const u16* __restrict__ A, const u16* __restrict__ Bt,
        const float* __restrict__ bias, OT* __restrict__ C, u16* __restrict__ Vt,
        int M, int N, int K, int ldc){
  __shared__ u16 As[64*64];
  __shared__ u16 Bs[128*64];
  const int nwg = gridDim.x * gridDim.y;
  const int id  = blockIdx.x + gridDim.x * blockIdx.y;
  const int nid = (id & 7) * (nwg >> 3) + (id >> 3);   // nwg % 8 == 0
  const int bx = nid % gridDim.x, by = nid / gridDim.x;
  const int tid = threadIdx.x, wv = tid>>6, ln = tid&63;
  const int lr = ln&15, g8 = (ln>>4)*8;
  const int m0 = bx*64, n0 = by*128;
  const int wr = (wv>>1)*32, wc = (wv&1)*64;
  const int lrow = ln>>3, lcol = ((ln&7) ^ lrow)*8;   // pre-swizzled source col
  const int swz = (lr&7)*8;
  f32x4 acc[2][4] = {};
  const int nk = K >> 6;
  for (int kt=0; kt<nk; ++kt){
    #pragma unroll
    for (int it=0; it<6; ++it){
      int chunk = wv*6 + it;
      if (chunk < 8){
        int row = chunk*8 + lrow;
        gll16(A + (size_t)(m0+row)*K + kt*64 + lcol, &As[chunk*512]);
      } else {
        int bc = chunk - 8;
        int row = bc*8 + lrow;
        gll16(Bt + (size_t)(n0+row)*K + kt*64 + lcol, &Bs[bc*512]);
      }
    }
    __syncthreads();
    #pragma unroll
    for (int ks=0; ks<2; ++ks){
      int off = (ks*32 + g8) ^ swz;
      bf16x8 af[2], bfr[4];
      #pragma unroll
      for (int mt=0;mt<2;++mt) af[mt]  = *(const bf16x8*)&As[(wr+mt*16+lr)*64 + off];
      #pragma unroll
      for (int nt=0;nt<4;++nt) bfr[nt] = *(const bf16x8*)&Bs[(wc+nt*16+lr)*64 + off];
      #pragma unroll
      for (int mt=0;mt<2;++mt)
        #pragma unroll
        for (int nt=0;nt<4;++nt)
          acc[mt][nt] = __builtin_amdgcn_mfma_f32_16x16x32_bf16(af[mt], bfr[nt], acc[mt][nt], 0,0,0);
    }
    __syncthreads();
  }
  if (Vt && n0 >= 1024){
    #pragma unroll
    for (int mt=0;mt<2;++mt){
      int row0 = m0 + wr + mt*16 + 4*(ln>>4);
      int tin  = row0 & 2047;
      int p0 = 4*((tin>>4)&1) + 8*((tin>>2)&3) + 32*(tin>>5);
      size_t vbase = (size_t)(row0 >> 11) * 512;
      #pragma unroll
      for (int nt=0;nt<4;++nt){
        int col = n0 + wc + nt*16 + lr;
        float bv = bias[col];
        int nlat = col - 1024;
        union { u16 s[4]; uint2 v; } pk;
        #pragma unroll
        for (int r=0;r<4;++r) pk.s[r] = f2bf(acc[mt][nt][r] + bv);
        *(uint2*)&Vt[(vbase + nlat)*2048 + p0] = pk.v;
      }
    }
  } else {
    #pragma unroll
    for (int mt=0;mt<2;++mt){
      int row = m0 + wr + mt*16 + 4*(ln>>4);
      #pragma unroll
      for (int nt=0;nt<4;++nt){
        int col = n0 + wc + nt*16 + lr;
        float bv = bias[col];
        #pragma unroll
        for (int r=0;r<4;++r){
          float v = acc[mt][nt][r] + bv;
          if constexpr (sizeof(OT) == 2) C[(size_t)(row+r)*ldc + col] = f2bf(v);
          else                           C[(size_t)(row+r)*ldc + col] = v;
        }
      }
    }
  }
}

// ---------- causal flash attention, rank-32 latent, 32 q-rows per wave ----------
// 256 thr = 2 subgroups x 2 waves; kt ≡ sg (mod 2); triple-buffered K/V,
// counted vmcnt(4) (T4), LPT qt=31-y with backfill (3 blocks/CU).
__global__ __launch_bounds__(256, 3) void attn_fwd(const u16* __restrict__ QKV,
            const u16* __restrict__ Vt, u16* __restrict__ Out){
  const int bh = blockIdx.x;
  const int qt = 31 - blockIdx.y;
  const int b = bh >> 4, h = bh & 15;
  const int tid = threadIdx.x, wv = tid>>6, ln = tid&63;
  const int sg = wv>>1, wvL = wv&1;
  const int lr = ln&15, gq = ln>>4;
  __shared__ __align__(16) char SMEM[49152];
  u16* KB0 = (u16*)(SMEM)         + (sg*3 + 0)*2048;
  u16* KB1 = (u16*)(SMEM)         + (sg*3 + 1)*2048;
  u16* KB2 = (u16*)(SMEM)         + (sg*3 + 2)*2048;
  u16* VB0 = (u16*)(SMEM + 24576) + (sg*3 + 0)*2048;
  u16* VB1 = (u16*)(SMEM + 24576) + (sg*3 + 1)*2048;
  u16* VB2 = (u16*)(SMEM + 24576) + (sg*3 + 2)*2048;
  const int q0 = qt*64;
  const size_t base = (size_t)(b*2048) * 1536;
  const u16* qrowA = QKV + base + (size_t)(q0 + wvL*32 + lr)*1536 + h*32;
  bf16x8 qfA = *(const bf16x8*)(qrowA + gq*8);
  bf16x8 qfB = *(const bf16x8*)(qrowA + (size_t)16*1536 + gq*8);
  const int qgA = q0 + wvL*32 + lr, qgB = qgA + 16;
  f32x4 oA0 = {}, oA1 = {}, oB0 = {}, oB1 = {};
  float lA = 0.f, lB = 0.f;
  const u16* ksrc = QKV + base + 512 + h*32;
  const u16* vsrc = Vt + (size_t)(bh*32)*2048;

  const int ci = wvL*64 + ln;
  const int rK = ci>>2, cK = 8*((ci&3) ^ (rK&3));
  const int rV = ci>>3, cV = 8*((ci&7) ^ (rV&7));

  int offK[4], offV[2][2];
  #pragma unroll
  for (int nt=0;nt<4;++nt)
    offK[nt] = (nt*16+lr)*64 + ((gq*16) ^ ((lr&3)<<4));
  #pragma unroll
  for (int dt=0;dt<2;++dt)
    #pragma unroll
    for (int c=0;c<2;++c)
      offV[dt][c] = (dt*16+lr)*128 + ((c*64 + gq*16) ^ ((lr&7)<<4));

  const u16* kpa = ksrc + (size_t)(sg*64 + rK)*1536 + cK;
  const u16* kpb = ksrc + (size_t)(sg*64 + 32 + rK)*1536 + cK;
  const u16* vpa = vsrc + (size_t)rV*2048 + sg*64 + cV;
  const u16* vpb = vsrc + (size_t)(16+rV)*2048 + sg*64 + cV;
  const size_t KSTEP = (size_t)128*1536;

  #define STG3(KBN, VBN) do { \
    gll16(kpa, (KBN) + wvL*512); \
    gll16(kpb, (KBN) + 1024 + wvL*512); \
    gll16(vpa, (VBN) + wvL*512); \
    gll16(vpb, (VBN) + 1024 + wvL*512); \
    kpa += KSTEP; kpb += KSTEP; vpa += 128; vpb += 128; \
  } while(0)

  if (sg <= qt)      STG3(KB0, VB0);
  if (sg + 2 <= qt){ STG3(KB1, VB1); WAITV4(); } else { WAITV0(); }
  BARRIER();

  #define ABODY(II, KBC, VBC, KBN, VBN) do { \
    const int kt = 2*(II) + sg; \
    const bool stg = (kt + 4 <= qt); \
    if (stg) STG3(KBN, VBN); \
    if (kt <= qt){ \
      f32x4 sA[4] = {}, sB[4] = {}; \
      __builtin_amdgcn_s_setprio(1); \
      _Pragma("unroll") for (int nt=0;nt<4;++nt){ \
        bf16x8 k0 = *(const bf16x8*)((const char*)(KBC) + offK[nt]); \
        sA[nt] = __builtin_amdgcn_mfma_f32_16x16x32_bf16(k0, qfA, sA[nt], 0,0,0); \
        sB[nt] = __builtin_amdgcn_mfma_f32_16x16x32_bf16(k0, qfB, sB[nt], 0,0,0); \
      } \
      __builtin_amdgcn_s_setprio(0); \
      if (kt == qt){ \
        const int kv0 = kt*64; \
        _Pragma("unroll") for (int nt=0;nt<4;++nt) \
        _Pragma("unroll") for (int r=0;r<4;++r){ \
          int k = kv0 + nt*16 + 4*gq + r; \
          if (k > qgA) sA[nt][r] = -1e30f; \
          if (k > qgB) sB[nt][r] = -1e30f; \
        } \
      } \
      union { u32 u[4]; bf16x8 v; } paA0, paA1, paB0, paB1; \
      { \
        float p0,p1,p2,p3,p4,p5,p6,p7; \
        p0=__builtin_amdgcn_exp2f(sA[0][0]); p1=__builtin_amdgcn_exp2f(sA[0][1]); \
        p2=__builtin_amdgcn_exp2f(sA[0][2]); p3=__builtin_amdgcn_exp2f(sA[0][3]); \
        p4=__builtin_amdgcn_exp2f(sA[1][0]); p5=__builtin_amdgcn_exp2f(sA[1][1]); \
        p6=__builtin_amdgcn_exp2f(sA[1][2]); p7=__builtin_amdgcn_exp2f(sA[1][3]); \
        lA += ((p0+p1)+(p2+p3)) + ((p4+p5)+(p6+p7)); \
        paA0.u[0]=cvtpk(p0,p1); paA0.u[1]=cvtpk(p2,p3); paA0.u[2]=cvtpk(p4,p5); paA0.u[3]=cvtpk(p6,p7); \
        p0=__builtin_amdgcn_exp2f(sA[2][0]); p1=__builtin_amdgcn_exp2f(sA[2][1]); \
        p2=__builtin_amdgcn_exp2f(sA[2][2]); p3=__builtin_amdgcn_exp2f(sA[2][3]); \
        p4=__builtin_amdgcn_exp2f(sA[3][0]); p5=__builtin_amdgcn_exp2f(sA[3][1]); \
        p6=__builtin_amdgcn_exp2f(sA[3][2]); p7=__builtin_amdgcn_exp2f(sA[3][3]); \
        lA += ((p0+p1)+(p2+p3)) + ((p4+p5)+(p6+p7)); \
        paA1.u[0]=cvtpk(p0,p1); paA1.u[1]=cvtpk(p2,p3); paA1.u[2]=cvtpk(p4,p5); paA1.u[3]=cvtpk(p6,p7); \
        p0=__builtin_amdgcn_exp2f(sB[0][0]); p1=__builtin_amdgcn_exp2f(sB[0][1]); \
        p2=__builtin_amdgcn_exp2f(sB[0][2]); p3=__builtin_amdgcn_exp2f(sB[0][3]); \
        p4=__builtin_amdgcn_exp2f(sB[1][0]); p5=__builtin_amdgcn_exp2f(sB[1][1]); \
        p6=__builtin_amdgcn_exp2f(sB[1][2]); p7=__builtin_amdgcn_exp2f(sB[1][3]); \
        lB += ((p0+p1)+(p2+p3)) + ((p4+p5)+(p6+p7)); \
        paB0.u[0]=cvtpk(p0,p1); paB0.u[1]=cvtpk(p2,p3); paB0.u[2]=cvtpk(p4,p5); paB0.u[3]=cvtpk(p6,p7); \
        p0=__builtin_amdgcn_exp2f(sB[2][0]); p1=__builtin_amdgcn_exp2f(sB[2][1]); \
        p2=__builtin_amdgcn_exp2f(sB[2][2]); p3=__builtin_amdgcn_exp2f(sB[2][3]); \
        p4=__builtin_amdgcn_exp2f(sB[3][0]); p5=__builtin_amdgcn_exp2f(sB[3][1]); \
        p6=__builtin_amdgcn_exp2f(sB[3][2]); p7=__builtin_amdgcn_exp2f(sB[3][3]); \
        lB += ((p0+p1)+(p2+p3)) + ((p4+p5)+(p6+p7)); \
        paB1.u[0]=cvtpk(p0,p1); paB1.u[1]=cvtpk(p2,p3); paB1.u[2]=cvtpk(p4,p5); paB1.u[3]=cvtpk(p6,p7); \
      } \
      __builtin_amdgcn_s_setprio(1); \
      { \
        bf16x8 v00 = *(const bf16x8*)((const char*)(VBC) + offV[0][0]); \
        bf16x8 v10 = *(const bf16x8*)((const char*)(VBC) + offV[1][0]); \
        bf16x8 v01 = *(const bf16x8*)((const char*)(VBC) + offV[0][1]); \
        bf16x8 v11 = *(const bf16x8*)((const char*)(VBC) + offV[1][1]); \
        oA0 = __builtin_amdgcn_mfma_f32_16x16x32_bf16(paA0.v, v00, oA0, 0,0,0); \
        oA1 = __builtin_amdgcn_mfma_f32_16x16x32_bf16(paA0.v, v10, oA1, 0,0,0); \
        oB0 = __builtin_amdgcn_mfma_f32_16x16x32_bf16(paB0.v, v00, oB0, 0,0,0); \
        oB1 = __builtin_amdgcn_mfma_f32_16x16x32_bf16(paB0.v, v10, oB1, 0,0,0); \
        oA0 = __builtin_amdgcn_mfma_f32_16x16x32_bf16(paA1.v, v01, oA0, 0,0,0); \
        oA1 = __builtin_amdgcn_mfma_f32_16x16x32_bf16(paA1.v, v11, oA1, 0,0,0); \
        oB0 = __builtin_amdgcn_mfma_f32_16x16x32_bf16(paB1.v, v01, oB0, 0,0,0); \
        oB1 = __builtin_amdgcn_mfma_f32_16x16x32_bf16(paB1.v, v11, oB1, 0,0,0); \
      } \
      __builtin_amdgcn_s_setprio(0); \
    } \
    if (stg) WAITV4(); else WAITV0(); \
    BARRIER(); \
  } while(0)

  const int nmax = (qt + 2) >> 1;
  const int jmax = (nmax + 2) / 3;
  for (int j = 0; j < jmax; ++j){
    ABODY(3*j+0, KB0, VB0, KB2, VB2);
    ABODY(3*j+1, KB1, VB1, KB0, VB0);
    ABODY(3*j+2, KB2, VB2, KB1, VB1);
  }
  lA += __shfl_xor(lA, 16); lA += __shfl_xor(lA, 32);
  lB += __shfl_xor(lB, 16); lB += __shfl_xor(lB, 32);

  float* MO = (float*)SMEM;               // [64][34] padded
  float* ML = (float*)(SMEM + 12288);     // l[64]
  if (sg == 1){
    #pragma unroll
    for (int r=0;r<4;++r){
      int rowA = wvL*32 + 4*gq + r;
      MO[rowA*34 + lr]            = oA0[r];
      MO[rowA*34 + 16 + lr]       = oA1[r];
      MO[(rowA+16)*34 + lr]       = oB0[r];
      MO[(rowA+16)*34 + 16 + lr]  = oB1[r];
    }
    if (gq == 0){ ML[wvL*32 + lr] = lA; ML[wvL*32 + 16 + lr] = lB; }
  }
  __syncthreads();
  if (sg == 0){
    float lSA = lA + ML[wvL*32 + lr];
    float lSB = lB + ML[wvL*32 + 16 + lr];
    float lA_o[4], lB_o[4];
    #pragma unroll
    for (int r=0;r<4;++r){ lA_o[r] = __shfl(lSA, 4*gq + r); lB_o[r] = __shfl(lSB, 4*gq + r); }
    #pragma unroll
    for (int r=0;r<4;++r){
      int rowA = wvL*32 + 4*gq + r;
      float vA0 = (oA0[r] + MO[rowA*34 + lr])           / lA_o[r];
      float vA1 = (oA1[r] + MO[rowA*34 + 16 + lr])      / lA_o[r];
      float vB0 = (oB0[r] + MO[(rowA+16)*34 + lr])      / lB_o[r];
      float vB1 = (oB1[r] + MO[(rowA+16)*34 + 16 + lr]) / lB_o[r];
      size_t obA = (size_t)(b*2048 + q0 + rowA)*512 + h*32;
      Out[obA + lr]      = f2bf(vA0);
      Out[obA + 16 + lr] = f2bf(vA1);
      size_t obB = obA + (size_t)16*512;
      Out[obB + lr]      = f2bf(vB0);
      Out[obB + 16 + lr] = f2bf(vB1);
    }
  }
}

// ---------- workspace layout (bytes) ----------
#define WS_B2   0u                                   // 1536*4
#define WS_WT   8192u                                // 1536*1024*2 = 3145728
#define WS_W2T  (WS_WT + 3145728u)                   // 1024*512*2  = 1048576
#define WS_XB   (WS_W2T + 1048576u)                  // 4096*1024*2 = 8388608
#define WS_QKV  (WS_XB + 8388608u)                   // 4096*1536*2 = 12582912
#define WS_VT   (WS_QKV + 12582912u)                 // 1024*2048*2 = 4194304
#define WS_ATT  (WS_VT + 4194304u)                   // 4096*512*2  = 4194304

extern "C" void kernel_launch(void* const* d_in, const int* in_sizes, int n_in,
                              void* d_out, int out_size, void* d_ws, size_t ws_size,
                              hipStream_t stream) {
  const float* x  = (const float*)d_in[0];
  const float* Wa = (const float*)d_in[1];
  const float* ba = (const float*)d_in[2];
  const float* Wp = (const float*)d_in[3];
  const float* bp = (const float*)d_in[4];
  const float* kc = (const float*)d_in[5];
  const float* ke = (const float*)d_in[6];
  const float* vc = (const float*)d_in[7];
  const float* ve = (const float*)d_in[8];
  float* out = (float*)d_out;
  char* ws = (char*)d_ws;
  float* b2  = (float*)(ws + WS_B2);
  u16* Wt    = (u16*)(ws + WS_WT);
  u16* W2t   = (u16*)(ws + WS_W2T);
  u16* Xb    = (u16*)(ws + WS_XB);
  u16* QKVb  = (u16*)(ws + WS_QKV);
  u16* Vt    = (u16*)(ws + WS_VT);
  u16* Att   = (u16*)(ws + WS_ATT);

  prep_x<<<1027, 256, 0, stream>>>(x, ba, kc, ke, vc, Xb, b2);
  fold_f32<<<dim3(16,64), 256, 0, stream>>>(Wa, Wp, kc, ke, vc, ve, Wt, W2t);
  gemm128<u16><<<dim3(32,12), 256, 0, stream>>>(Xb, Wt, b2, QKVb, Vt, 4096, 1536, 1024, 1536);
  attn_fwd<<<dim3(32,32), 256, 0, stream>>>(QKVb, Vt, Att);
  gemm64<float><<<dim3(64,8), 256, 0, stream>>>(Att, W2t, bp, out, (u16*)nullptr, 4096, 1024, 512, 1024);
}

// Round 22
// 69.066 us; speedup vs baseline: 1.0386x; 1.0386x over previous
//
#include <hip/hip_runtime.h>
#include <cstddef>

typedef __attribute__((ext_vector_type(8))) __bf16 bf16x8;
typedef __attribute__((ext_vector_type(4))) float f32x4;
typedef unsigned short u16;
typedef unsigned int   u32;

#define SCLF (0.125f * 1.44269504f)   // softmax scale * log2(e), baked into q' master weights

// ---------- helpers ----------
__device__ __forceinline__ u16 f2bf(float f){
  union { float f; u32 u; } v; v.f = f;
  u32 r = v.u + 0x7FFFu + ((v.u >> 16) & 1u);   // RNE
  return (u16)(r >> 16);
}
__device__ __forceinline__ u32 cvtpk(float lo, float hi){
  u32 r; asm("v_cvt_pk_bf16_f32 %0, %1, %2" : "=v"(r) : "v"(lo), "v"(hi)); return r;
}
__device__ __forceinline__ void gll16(const void* g, void* l){
  __builtin_amdgcn_global_load_lds((__attribute__((address_space(1))) void*)g,
                                   (__attribute__((address_space(3))) void*)l, 16, 0, 0);
}
#define BARRIER() asm volatile("s_barrier" ::: "memory")
#define WAITV4()  asm volatile("s_waitcnt vmcnt(4)" ::: "memory")
#define WAITV0()  asm volatile("s_waitcnt vmcnt(0)" ::: "memory")

// ---------- prep_x: x fp32->bf16 (1024 blocks, 4 float4/thread) + bias fold (3 blocks) ----------
__global__ __launch_bounds__(256) void prep_x(const float* __restrict__ x,
      const float* __restrict__ ba, const float* __restrict__ kc,
      const float* __restrict__ ke, const float* __restrict__ vc,
      u16* __restrict__ Xb, float* __restrict__ b2){
  __shared__ float SH[3104];           // BaL[1024] + W65[32*65] = 12416 B
  const int bid = blockIdx.x, tid = threadIdx.x;
  if (bid < 1024){
    int i0 = bid*1024 + tid;
    #pragma unroll
    for (int t=0;t<4;++t){
      int i = i0 + t*256;
      float4 v = ((const float4*)x)[i];
      uint2 r; r.x = cvtpk(v.x, v.y); r.y = cvtpk(v.z, v.w);
      ((uint2*)Xb)[i] = r;
    }
  } else {
    const int part = bid - 1024;
    float* BaL = SH;                   // [1024]
    float* W65 = SH + 1024;            // [32][65]
    *(float4*)&BaL[tid*4] = *(const float4*)&ba[part*1024 + tid*4];
    {
      const float* msrc = (part==0) ? ke : (part==1) ? kc : vc;
      #pragma unroll
      for (int i=0;i<8;++i){
        int idx = tid + i*256;
        float v = msrc[idx];
        int r, d;
        if (part == 0){ r = idx >> 6; d = idx & 63; }
        else          { d = idx >> 5; r = idx & 31; }
        W65[r*65 + d] = v;
      }
    }
    __syncthreads();
    const float scl = (part==0) ? SCLF : 1.f;
    #pragma unroll
    for (int t=0;t<2;++t){
      int l = tid + t*256;
      int hh = l >> 5, r = l & 31;
      float acc = 0.f;
      for (int d=0;d<64;++d) acc += BaL[hh*64 + d] * W65[r*65 + d];
      b2[part*512 + l] = acc * scl;
    }
  }
}

// ---------- fold_f32: weight folds reading f32 inputs directly ----------
// grid (16 cc, 64 y): y<48 qkv fold (ph=y), y>=48 proj fold (ph=y-48).
__global__ __launch_bounds__(256) void fold_f32(const float* __restrict__ Wa,
      const float* __restrict__ Wp, const float* __restrict__ kc,
      const float* __restrict__ ke, const float* __restrict__ vc,
      const float* __restrict__ ve, u16* __restrict__ Wt, u16* __restrict__ W2t){
  __shared__ __align__(16) char PS[28928];   // SH f32 [64][65] | As [64][64] u16 | Bs [32][64] u16
  float* SH = (float*)PS;
  u16* As = (u16*)(PS + 16640);
  u16* Bs = (u16*)(PS + 16640 + 8192);
  const int cc = blockIdx.x, y = blockIdx.y;
  const int tid = threadIdx.x;
  const int wv = tid>>6, ln = tid&63;
  const int lr = ln&15, g8 = (ln>>4)*8, gq = ln>>4;
  const int swz = (lr&7)*8;
  const int c0 = cc*64;

  if (y < 48){                         // ---- qkv fold ----
    const int ph = y;
    const int part = ph >> 4;
    {
      int r = tid>>3, d8 = tid&7;
      float v[8];
      if (part == 0){
        #pragma unroll
        for (int j=0;j<8;++j) v[j] = ke[r*64 + d8*8 + j]*SCLF;
      } else {
        const float* m = (part==1) ? kc : vc;
        #pragma unroll
        for (int j=0;j<8;++j) v[j] = m[(d8*8+j)*32 + r];
      }
      uint4 w; w.x=cvtpk(v[0],v[1]); w.y=cvtpk(v[2],v[3]); w.z=cvtpk(v[4],v[5]); w.w=cvtpk(v[6],v[7]);
      *(uint4*)&Bs[r*64 + ((d8 ^ (r&7))*8)] = w;
    }
    #pragma unroll
    for (int p=0;p<2;++p){
      int g2 = p*256 + tid;
      int row = g2>>3, gcol = g2&7;
      const float* src = Wa + (size_t)(c0+row)*3072 + ph*64 + gcol*8;
      float4 a = ((const float4*)src)[0], b = ((const float4*)src)[1];
      uint4 w; w.x=cvtpk(a.x,a.y); w.y=cvtpk(a.z,a.w); w.z=cvtpk(b.x,b.y); w.w=cvtpk(b.z,b.w);
      *(uint4*)&As[row*64 + ((gcol ^ (row&7))*8)] = w;
    }
    __syncthreads();
    f32x4 acc[2] = {};
    const int wr = (wv>>1)*32, wn = wv&1;
    #pragma unroll
    for (int ks=0;ks<2;++ks){
      int off = (ks*32 + g8) ^ swz;
      bf16x8 bf = *(const bf16x8*)&Bs[(wn*16+lr)*64 + off];
      #pragma unroll
      for (int mt=0;mt<2;++mt){
        bf16x8 af = *(const bf16x8*)&As[(wr+mt*16+lr)*64 + off];
        acc[mt] = __builtin_amdgcn_mfma_f32_16x16x32_bf16(af, bf, acc[mt], 0,0,0);
      }
    }
    const int n = part*512 + (ph&15)*32 + wn*16 + lr;
    #pragma unroll
    for (int mt=0;mt<2;++mt){
      union { u16 s[4]; uint2 v; } pk;
      #pragma unroll
      for (int r=0;r<4;++r) pk.s[r] = f2bf(acc[mt][r]);
      *(uint2*)&Wt[(size_t)n*1024 + c0 + wr + mt*16 + 4*gq] = pk.v;
    }
  } else {                             // ---- proj fold ----
    const int ph = y - 48;                       // 0..15
    {
      int r = tid>>2, c4 = (tid&3)*16;
      const float* src = Wp + (size_t)(ph*64 + r)*1024 + c0 + c4;
      float4 v0 = ((const float4*)src)[0], v1 = ((const float4*)src)[1],
             v2 = ((const float4*)src)[2], v3 = ((const float4*)src)[3];
      float* dst = &SH[r*65 + c4];
      dst[0]=v0.x; dst[1]=v0.y; dst[2]=v0.z; dst[3]=v0.w;
      dst[4]=v1.x; dst[5]=v1.y; dst[6]=v1.z; dst[7]=v1.w;
      dst[8]=v2.x; dst[9]=v2.y; dst[10]=v2.z; dst[11]=v2.w;
      dst[12]=v3.x; dst[13]=v3.y; dst[14]=v3.z; dst[15]=v3.w;
    }
    {
      int r = tid>>3, d8 = tid&7;
      float v[8];
      #pragma unroll
      for (int j=0;j<8;++j) v[j] = ve[r*64 + d8*8 + j];
      uint4 w; w.x=cvtpk(v[0],v[1]); w.y=cvtpk(v[2],v[3]); w.z=cvtpk(v[4],v[5]); w.w=cvtpk(v[6],v[7]);
      *(uint4*)&Bs[r*64 + ((d8 ^ (r&7))*8)] = w;
    }
    __syncthreads();
    #pragma unroll
    for (int p=0;p<2;++p){
      int g2 = p*256 + tid;
      int j = g2>>3, d8 = g2&7;
      float v[8];
      #pragma unroll
      for (int jj=0;jj<8;++jj) v[jj] = SH[(d8*8+jj)*65 + j];
      uint4 w; w.x=cvtpk(v[0],v[1]); w.y=cvtpk(v[2],v[3]); w.z=cvtpk(v[4],v[5]); w.w=cvtpk(v[6],v[7]);
      *(uint4*)&As[j*64 + ((d8 ^ (j&7))*8)] = w;
    }
    __syncthreads();
    f32x4 acc[2] = {};
    const int wr = (wv>>1)*32, wn = wv&1;
    #pragma unroll
    for (int ks=0;ks<2;++ks){
      int off = (ks*32 + g8) ^ swz;
      bf16x8 bf = *(const bf16x8*)&Bs[(wn*16+lr)*64 + off];
      #pragma unroll
      for (int mt=0;mt<2;++mt){
        bf16x8 af = *(const bf16x8*)&As[(wr+mt*16+lr)*64 + off];
        acc[mt] = __builtin_amdgcn_mfma_f32_16x16x32_bf16(af, bf, acc[mt], 0,0,0);
      }
    }
    const int col = ph*32 + wn*16 + lr;
    #pragma unroll
    for (int mt=0;mt<2;++mt)
      #pragma unroll
      for (int r=0;r<4;++r)
        W2t[(size_t)(c0 + wr + mt*16 + 4*gq + r)*512 + col] = f2bf(acc[mt][r]);
  }
}

// ---------- 64x128 bf16 GEMM (2-phase, gll16, T2-swizzled LDS): C = A*Bt^T + bias ----------
template<typename OT>
__global__ __launch_bounds__(256) void gemm64(const u16* __restrict__ A, const u16* __restrict__ Bt,
        const float* __restrict__ bias, OT* __restrict__ C, u16* __restrict__ Vt,
        int M, int N, int K, int ldc){
  __shared__ u16 As[64*64];
  __shared__ u16 Bs[128*64];
  const int nwg = gridDim.x * gridDim.y;
  const int id  = blockIdx.x + gridDim.x * blockIdx.y;
  const int nid = (id & 7) * (nwg >> 3) + (id >> 3);   // nwg % 8 == 0
  const int bx = nid % gridDim.x, by = nid / gridDim.x;
  const int tid = threadIdx.x, wv = tid>>6, ln = tid&63;
  const int lr = ln&15, g8 = (ln>>4)*8;
  const int m0 = bx*64, n0 = by*128;
  const int wr = (wv>>1)*32, wc = (wv&1)*64;
  const int lrow = ln>>3, lcol = ((ln&7) ^ lrow)*8;   // pre-swizzled source col
  const int swz = (lr&7)*8;
  f32x4 acc[2][4] = {};
  const int nk = K >> 6;
  for (int kt=0; kt<nk; ++kt){
    #pragma unroll
    for (int it=0; it<6; ++it){
      int chunk = wv*6 + it;
      if (chunk < 8){
        int row = chunk*8 + lrow;
        gll16(A + (size_t)(m0+row)*K + kt*64 + lcol, &As[chunk*512]);
      } else {
        int bc = chunk - 8;
        int row = bc*8 + lrow;
        gll16(Bt + (size_t)(n0+row)*K + kt*64 + lcol, &Bs[bc*512]);
      }
    }
    __syncthreads();
    #pragma unroll
    for (int ks=0; ks<2; ++ks){
      int off = (ks*32 + g8) ^ swz;
      bf16x8 af[2], bfr[4];
      #pragma unroll
      for (int mt=0;mt<2;++mt) af[mt]  = *(const bf16x8*)&As[(wr+mt*16+lr)*64 + off];
      #pragma unroll
      for (int nt=0;nt<4;++nt) bfr[nt] = *(const bf16x8*)&Bs[(wc+nt*16+lr)*64 + off];
      #pragma unroll
      for (int mt=0;mt<2;++mt)
        #pragma unroll
        for (int nt=0;nt<4;++nt)
          acc[mt][nt] = __builtin_amdgcn_mfma_f32_16x16x32_bf16(af[mt], bfr[nt], acc[mt][nt], 0,0,0);
    }
    __syncthreads();
  }
  if (Vt && n0 >= 1024){
    #pragma unroll
    for (int mt=0;mt<2;++mt){
      int row0 = m0 + wr + mt*16 + 4*(ln>>4);
      int tin  = row0 & 2047;
      int p0 = 4*((tin>>4)&1) + 8*((tin>>2)&3) + 32*(tin>>5);
      size_t vbase = (size_t)(row0 >> 11) * 512;
      #pragma unroll
      for (int nt=0;nt<4;++nt){
        int col = n0 + wc + nt*16 + lr;
        float bv = bias[col];
        int nlat = col - 1024;
        union { u16 s[4]; uint2 v; } pk;
        #pragma unroll
        for (int r=0;r<4;++r) pk.s[r] = f2bf(acc[mt][nt][r] + bv);
        *(uint2*)&Vt[(vbase + nlat)*2048 + p0] = pk.v;
      }
    }
  } else {
    #pragma unroll
    for (int mt=0;mt<2;++mt){
      int row = m0 + wr + mt*16 + 4*(ln>>4);
      #pragma unroll
      for (int nt=0;nt<4;++nt){
        int col = n0 + wc + nt*16 + lr;
        float bv = bias[col];
        #pragma unroll
        for (int r=0;r<4;++r){
          float v = acc[mt][nt][r] + bv;
          if constexpr (sizeof(OT) == 2) C[(size_t)(row+r)*ldc + col] = f2bf(v);
          else                           C[(size_t)(row+r)*ldc + col] = v;
        }
      }
    }
  }
}

// ---------- causal flash attention, rank-32 latent, 32 q-rows per wave ----------
// 256 thr = 2 subgroups x 2 waves; kt ≡ sg (mod 2); triple-buffered K/V,
// counted vmcnt(4) (T4), LPT qt=31-y with backfill (3 blocks/CU).
__global__ __launch_bounds__(256, 3) void attn_fwd(const u16* __restrict__ QKV,
            const u16* __restrict__ Vt, u16* __restrict__ Out){
  const int bh = blockIdx.x;
  const int qt = 31 - blockIdx.y;
  const int b = bh >> 4, h = bh & 15;
  const int tid = threadIdx.x, wv = tid>>6, ln = tid&63;
  const int sg = wv>>1, wvL = wv&1;
  const int lr = ln&15, gq = ln>>4;
  __shared__ __align__(16) char SMEM[49152];
  u16* KB0 = (u16*)(SMEM)         + (sg*3 + 0)*2048;
  u16* KB1 = (u16*)(SMEM)         + (sg*3 + 1)*2048;
  u16* KB2 = (u16*)(SMEM)         + (sg*3 + 2)*2048;
  u16* VB0 = (u16*)(SMEM + 24576) + (sg*3 + 0)*2048;
  u16* VB1 = (u16*)(SMEM + 24576) + (sg*3 + 1)*2048;
  u16* VB2 = (u16*)(SMEM + 24576) + (sg*3 + 2)*2048;
  const int q0 = qt*64;
  const size_t base = (size_t)(b*2048) * 1536;
  const u16* qrowA = QKV + base + (size_t)(q0 + wvL*32 + lr)*1536 + h*32;
  bf16x8 qfA = *(const bf16x8*)(qrowA + gq*8);
  bf16x8 qfB = *(const bf16x8*)(qrowA + (size_t)16*1536 + gq*8);
  const int qgA = q0 + wvL*32 + lr, qgB = qgA + 16;
  f32x4 oA0 = {}, oA1 = {}, oB0 = {}, oB1 = {};
  float lA = 0.f, lB = 0.f;
  const u16* ksrc = QKV + base + 512 + h*32;
  const u16* vsrc = Vt + (size_t)(bh*32)*2048;

  const int ci = wvL*64 + ln;
  const int rK = ci>>2, cK = 8*((ci&3) ^ (rK&3));
  const int rV = ci>>3, cV = 8*((ci&7) ^ (rV&7));

  int offK[4], offV[2][2];
  #pragma unroll
  for (int nt=0;nt<4;++nt)
    offK[nt] = (nt*16+lr)*64 + ((gq*16) ^ ((lr&3)<<4));
  #pragma unroll
  for (int dt=0;dt<2;++dt)
    #pragma unroll
    for (int c=0;c<2;++c)
      offV[dt][c] = (dt*16+lr)*128 + ((c*64 + gq*16) ^ ((lr&7)<<4));

  const u16* kpa = ksrc + (size_t)(sg*64 + rK)*1536 + cK;
  const u16* kpb = ksrc + (size_t)(sg*64 + 32 + rK)*1536 + cK;
  const u16* vpa = vsrc + (size_t)rV*2048 + sg*64 + cV;
  const u16* vpb = vsrc + (size_t)(16+rV)*2048 + sg*64 + cV;
  const size_t KSTEP = (size_t)128*1536;

  #define STG3(KBN, VBN) do { \
    gll16(kpa, (KBN) + wvL*512); \
    gll16(kpb, (KBN) + 1024 + wvL*512); \
    gll16(vpa, (VBN) + wvL*512); \
    gll16(vpb, (VBN) + 1024 + wvL*512); \
    kpa += KSTEP; kpb += KSTEP; vpa += 128; vpb += 128; \
  } while(0)

  if (sg <= qt)      STG3(KB0, VB0);
  if (sg + 2 <= qt){ STG3(KB1, VB1); WAITV4(); } else { WAITV0(); }
  BARRIER();

  #define ABODY(II, KBC, VBC, KBN, VBN) do { \
    const int kt = 2*(II) + sg; \
    const bool stg = (kt + 4 <= qt); \
    if (stg) STG3(KBN, VBN); \
    if (kt <= qt){ \
      f32x4 sA[4] = {}, sB[4] = {}; \
      __builtin_amdgcn_s_setprio(1); \
      _Pragma("unroll") for (int nt=0;nt<4;++nt){ \
        bf16x8 k0 = *(const bf16x8*)((const char*)(KBC) + offK[nt]); \
        sA[nt] = __builtin_amdgcn_mfma_f32_16x16x32_bf16(k0, qfA, sA[nt], 0,0,0); \
        sB[nt] = __builtin_amdgcn_mfma_f32_16x16x32_bf16(k0, qfB, sB[nt], 0,0,0); \
      } \
      __builtin_amdgcn_s_setprio(0); \
      if (kt == qt){ \
        const int kv0 = kt*64; \
        _Pragma("unroll") for (int nt=0;nt<4;++nt) \
        _Pragma("unroll") for (int r=0;r<4;++r){ \
          int k = kv0 + nt*16 + 4*gq + r; \
          if (k > qgA) sA[nt][r] = -1e30f; \
          if (k > qgB) sB[nt][r] = -1e30f; \
        } \
      } \
      union { u32 u[4]; bf16x8 v; } paA0, paA1, paB0, paB1; \
      { \
        float p0,p1,p2,p3,p4,p5,p6,p7; \
        p0=__builtin_amdgcn_exp2f(sA[0][0]); p1=__builtin_amdgcn_exp2f(sA[0][1]); \
        p2=__builtin_amdgcn_exp2f(sA[0][2]); p3=__builtin_amdgcn_exp2f(sA[0][3]); \
        p4=__builtin_amdgcn_exp2f(sA[1][0]); p5=__builtin_amdgcn_exp2f(sA[1][1]); \
        p6=__builtin_amdgcn_exp2f(sA[1][2]); p7=__builtin_amdgcn_exp2f(sA[1][3]); \
        lA += ((p0+p1)+(p2+p3)) + ((p4+p5)+(p6+p7)); \
        paA0.u[0]=cvtpk(p0,p1); paA0.u[1]=cvtpk(p2,p3); paA0.u[2]=cvtpk(p4,p5); paA0.u[3]=cvtpk(p6,p7); \
        p0=__builtin_amdgcn_exp2f(sA[2][0]); p1=__builtin_amdgcn_exp2f(sA[2][1]); \
        p2=__builtin_amdgcn_exp2f(sA[2][2]); p3=__builtin_amdgcn_exp2f(sA[2][3]); \
        p4=__builtin_amdgcn_exp2f(sA[3][0]); p5=__builtin_amdgcn_exp2f(sA[3][1]); \
        p6=__builtin_amdgcn_exp2f(sA[3][2]); p7=__builtin_amdgcn_exp2f(sA[3][3]); \
        lA += ((p0+p1)+(p2+p3)) + ((p4+p5)+(p6+p7)); \
        paA1.u[0]=cvtpk(p0,p1); paA1.u[1]=cvtpk(p2,p3); paA1.u[2]=cvtpk(p4,p5); paA1.u[3]=cvtpk(p6,p7); \
        p0=__builtin_amdgcn_exp2f(sB[0][0]); p1=__builtin_amdgcn_exp2f(sB[0][1]); \
        p2=__builtin_amdgcn_exp2f(sB[0][2]); p3=__builtin_amdgcn_exp2f(sB[0][3]); \
        p4=__builtin_amdgcn_exp2f(sB[1][0]); p5=__builtin_amdgcn_exp2f(sB[1][1]); \
        p6=__builtin_amdgcn_exp2f(sB[1][2]); p7=__builtin_amdgcn_exp2f(sB[1][3]); \
        lB += ((p0+p1)+(p2+p3)) + ((p4+p5)+(p6+p7)); \
        paB0.u[0]=cvtpk(p0,p1); paB0.u[1]=cvtpk(p2,p3); paB0.u[2]=cvtpk(p4,p5); paB0.u[3]=cvtpk(p6,p7); \
        p0=__builtin_amdgcn_exp2f(sB[2][0]); p1=__builtin_amdgcn_exp2f(sB[2][1]); \
        p2=__builtin_amdgcn_exp2f(sB[2][2]); p3=__builtin_amdgcn_exp2f(sB[2][3]); \
        p4=__builtin_amdgcn_exp2f(sB[3][0]); p5=__builtin_amdgcn_exp2f(sB[3][1]); \
        p6=__builtin_amdgcn_exp2f(sB[3][2]); p7=__builtin_amdgcn_exp2f(sB[3][3]); \
        lB += ((p0+p1)+(p2+p3)) + ((p4+p5)+(p6+p7)); \
        paB1.u[0]=cvtpk(p0,p1); paB1.u[1]=cvtpk(p2,p3); paB1.u[2]=cvtpk(p4,p5); paB1.u[3]=cvtpk(p6,p7); \
      } \
      __builtin_amdgcn_s_setprio(1); \
      { \
        bf16x8 v00 = *(const bf16x8*)((const char*)(VBC) + offV[0][0]); \
        bf16x8 v10 = *(const bf16x8*)((const char*)(VBC) + offV[1][0]); \
        bf16x8 v01 = *(const bf16x8*)((const char*)(VBC) + offV[0][1]); \
        bf16x8 v11 = *(const bf16x8*)((const char*)(VBC) + offV[1][1]); \
        oA0 = __builtin_amdgcn_mfma_f32_16x16x32_bf16(paA0.v, v00, oA0, 0,0,0); \
        oA1 = __builtin_amdgcn_mfma_f32_16x16x32_bf16(paA0.v, v10, oA1, 0,0,0); \
        oB0 = __builtin_amdgcn_mfma_f32_16x16x32_bf16(paB0.v, v00, oB0, 0,0,0); \
        oB1 = __builtin_amdgcn_mfma_f32_16x16x32_bf16(paB0.v, v10, oB1, 0,0,0); \
        oA0 = __builtin_amdgcn_mfma_f32_16x16x32_bf16(paA1.v, v01, oA0, 0,0,0); \
        oA1 = __builtin_amdgcn_mfma_f32_16x16x32_bf16(paA1.v, v11, oA1, 0,0,0); \
        oB0 = __builtin_amdgcn_mfma_f32_16x16x32_bf16(paB1.v, v01, oB0, 0,0,0); \
        oB1 = __builtin_amdgcn_mfma_f32_16x16x32_bf16(paB1.v, v11, oB1, 0,0,0); \
      } \
      __builtin_amdgcn_s_setprio(0); \
    } \
    if (stg) WAITV4(); else WAITV0(); \
    BARRIER(); \
  } while(0)

  const int nmax = (qt + 2) >> 1;
  const int jmax = (nmax + 2) / 3;
  for (int j = 0; j < jmax; ++j){
    ABODY(3*j+0, KB0, VB0, KB2, VB2);
    ABODY(3*j+1, KB1, VB1, KB0, VB0);
    ABODY(3*j+2, KB2, VB2, KB1, VB1);
  }
  lA += __shfl_xor(lA, 16); lA += __shfl_xor(lA, 32);
  lB += __shfl_xor(lB, 16); lB += __shfl_xor(lB, 32);

  float* MO = (float*)SMEM;               // [64][34] padded
  float* ML = (float*)(SMEM + 12288);     // l[64]
  if (sg == 1){
    #pragma unroll
    for (int r=0;r<4;++r){
      int rowA = wvL*32 + 4*gq + r;
      MO[rowA*34 + lr]            = oA0[r];
      MO[rowA*34 + 16 + lr]       = oA1[r];
      MO[(rowA+16)*34 + lr]       = oB0[r];
      MO[(rowA+16)*34 + 16 + lr]  = oB1[r];
    }
    if (gq == 0){ ML[wvL*32 + lr] = lA; ML[wvL*32 + 16 + lr] = lB; }
  }
  __syncthreads();
  if (sg == 0){
    float lSA = lA + ML[wvL*32 + lr];
    float lSB = lB + ML[wvL*32 + 16 + lr];
    float lA_o[4], lB_o[4];
    #pragma unroll
    for (int r=0;r<4;++r){ lA_o[r] = __shfl(lSA, 4*gq + r); lB_o[r] = __shfl(lSB, 4*gq + r); }
    #pragma unroll
    for (int r=0;r<4;++r){
      int rowA = wvL*32 + 4*gq + r;
      float vA0 = (oA0[r] + MO[rowA*34 + lr])           / lA_o[r];
      float vA1 = (oA1[r] + MO[rowA*34 + 16 + lr])      / lA_o[r];
      float vB0 = (oB0[r] + MO[(rowA+16)*34 + lr])      / lB_o[r];
      float vB1 = (oB1[r] + MO[(rowA+16)*34 + 16 + lr]) / lB_o[r];
      size_t obA = (size_t)(b*2048 + q0 + rowA)*512 + h*32;
      Out[obA + lr]      = f2bf(vA0);
      Out[obA + 16 + lr] = f2bf(vA1);
      size_t obB = obA + (size_t)16*512;
      Out[obB + lr]      = f2bf(vB0);
      Out[obB + 16 + lr] = f2bf(vB1);
    }
  }
}

// ---------- workspace layout (bytes) ----------
#define WS_B2   0u                                   // 1536*4
#define WS_WT   8192u                                // 1536*1024*2 = 3145728
#define WS_W2T  (WS_WT + 3145728u)                   // 1024*512*2  = 1048576
#define WS_XB   (WS_W2T + 1048576u)                  // 4096*1024*2 = 8388608
#define WS_QKV  (WS_XB + 8388608u)                   // 4096*1536*2 = 12582912
#define WS_VT   (WS_QKV + 12582912u)                 // 1024*2048*2 = 4194304
#define WS_ATT  (WS_VT + 4194304u)                   // 4096*512*2  = 4194304

extern "C" void kernel_launch(void* const* d_in, const int* in_sizes, int n_in,
                              void* d_out, int out_size, void* d_ws, size_t ws_size,
                              hipStream_t stream) {
  const float* x  = (const float*)d_in[0];
  const float* Wa = (const float*)d_in[1];
  const float* ba = (const float*)d_in[2];
  const float* Wp = (const float*)d_in[3];
  const float* bp = (const float*)d_in[4];
  const float* kc = (const float*)d_in[5];
  const float* ke = (const float*)d_in[6];
  const float* vc = (const float*)d_in[7];
  const float* ve = (const float*)d_in[8];
  float* out = (float*)d_out;
  char* ws = (char*)d_ws;
  float* b2  = (float*)(ws + WS_B2);
  u16* Wt    = (u16*)(ws + WS_WT);
  u16* W2t   = (u16*)(ws + WS_W2T);
  u16* Xb    = (u16*)(ws + WS_XB);
  u16* QKVb  = (u16*)(ws + WS_QKV);
  u16* Vt    = (u16*)(ws + WS_VT);
  u16* Att   = (u16*)(ws + WS_ATT);

  prep_x<<<1027, 256, 0, stream>>>(x, ba, kc, ke, vc, Xb, b2);
  fold_f32<<<dim3(16,64), 256, 0, stream>>>(Wa, Wp, kc, ke, vc, ve, Wt, W2t);
  gemm64<u16><<<dim3(64,12), 256, 0, stream>>>(Xb, Wt, b2, QKVb, Vt, 4096, 1536, 1024, 1536);
  attn_fwd<<<dim3(32,32), 256, 0, stream>>>(QKVb, Vt, Att);
  gemm64<float><<<dim3(64,8), 256, 0, stream>>>(Att, W2t, bp, out, (u16*)nullptr, 4096, 1024, 512, 1024);
}